// Round 21
// baseline (160.814 us; speedup 1.0000x reference)
//
#include <hip/hip_runtime.h>
#include <stdint.h>

#define N_NODES 50000
#define N_EDGES 800000
#define IN_DIM 128
#define HID_DIM 128
#define OUT_DIM 64

#define ELL_CAP 64                            // slots/row; Poisson(16) max deg ~38
#define XCD_GROUPS 8
#define ROWS_PER_XCD (N_NODES / XCD_GROUPS)   // 6250 exactly
#define SCAT_BLOCKS_PER_XCD 256
#define SCAT_BLOCKS (SCAT_BLOCKS_PER_XCD * XCD_GROUPS)   // 2048

#define INIT_BLOCKS 3300                      // 3300*256 = 844800 >= N_EDGES

typedef short bf16x8 __attribute__((ext_vector_type(8)));
typedef float f32x4  __attribute__((ext_vector_type(4)));

__device__ __forceinline__ uint32_t pack_bf16x2(float a, float b) {
    uint32_t ba = __float_as_uint(a), bb = __float_as_uint(b);
    ba = (ba + 0x7fffu + ((ba >> 16) & 1u)) >> 16;           // RNE low half
    bb = (bb + 0x7fffu + ((bb >> 16) & 1u)) & 0xffff0000u;   // RNE high half
    return ba | bb;
}

__device__ __forceinline__ unsigned short f2bf(float f) {
    uint32_t u = __float_as_uint(f);
    return (unsigned short)((u + 0x7fffu + ((u >> 16) & 1u)) >> 16);
}

// f32 -> fp8 e4m3fn, RNE, subnormals flushed, clamp at 448 (t1 ~ N(0,1): safe)
__device__ __forceinline__ uint8_t f2fp8(float f) {
    uint32_t u = __float_as_uint(f);
    uint32_t s = (u >> 24) & 0x80u;
    uint32_t au = u & 0x7fffffffu;
    uint32_t r = au + 0x7FFFFu + ((au >> 20) & 1u);   // RNE at dropped-20-bits boundary
    int e = (int)((r >> 23) & 0xffu) - 120;           // e_f32 - 127 + 7
    uint32_t m = (r >> 20) & 7u;
    uint32_t out;
    if (e <= 0) out = 0u;                             // flush tiny
    else if (e >= 16) out = 0x7Eu;                    // clamp to 448
    else out = ((uint32_t)e << 3) | m;
    return (uint8_t)(s | out);
}

// packed edge: high 16 bits = bf16(val), low 16 bits = col (col < 65536)
__device__ __forceinline__ uint32_t pack_edge(int col, float v) {
    uint32_t fb = __float_as_uint(v);
    fb = (fb + 0x7fffu + ((fb >> 16) & 1u)) & 0xffff0000u;
    return fb | (uint32_t)col;
}

// ---------------- fused init: zero counts + convert weights + pre-pack (col,val) ----------------

__global__ __launch_bounds__(256) void init_all(int* __restrict__ counts,
                                                const float* __restrict__ W1,
                                                const float* __restrict__ W2,
                                                unsigned short* __restrict__ wt1,
                                                unsigned short* __restrict__ wt2,
                                                const int* __restrict__ col,
                                                const float* __restrict__ vals,
                                                uint32_t* __restrict__ epk) {
    int i = blockIdx.x * 256 + threadIdx.x;
    if (i < N_NODES) counts[i] = 0;
    int j = i - N_NODES;
    if (j >= 0 && j < 128 * 128) {
        int n = j >> 7, k = j & 127;
        wt1[j] = f2bf(W1[k * 128 + n]);
    }
    int l = j - 128 * 128;
    if (l >= 0 && l < 64 * 128) {
        int n = l >> 7, k = l & 127;
        wt2[l] = f2bf(W2[k * 64 + n]);
    }
    if (i < N_EDGES) epk[i] = pack_edge(col[i], vals[i]);   // INIT_BLOCKS*256 >= N_EDGES
}

// ---------------- ELL build: single scatter pass, XCD-partitioned dest (structural floor ~40us) ----------------

__global__ __launch_bounds__(256) void scatter_ell(const int* __restrict__ row,
                                                   const uint32_t* __restrict__ epk,
                                                   int* __restrict__ counts,
                                                   uint32_t* __restrict__ ell) {
    const int xcd = blockIdx.x & (XCD_GROUPS - 1);
    const int blk = blockIdx.x >> 3;
    const int rlo = xcd * ROWS_PER_XCD;
    int e = blk * 256 + threadIdx.x;
    const int stride = SCAT_BLOCKS_PER_XCD * 256;
    for (; e < N_EDGES; e += stride) {
        int r = row[e];
        if ((unsigned)(r - rlo) < (unsigned)ROWS_PER_XCD) {
            int p = atomicAdd(&counts[r], 1);
            if (p < ELL_CAP)   // unreachable for Poisson(16); memory-safety guard
                ell[((size_t)r << 6) + p] = epk[e];
        }
    }
}

// ---------------- gemm1: {t1a,t1b}[M,64](fp8 e4m3) = fp8(x @ W1), column-split ----------------
// blockIdx.y==0 -> dims 0..63 -> t1a ; ==1 -> dims 64..127 -> t1b (each 3.2MB, L2-fit)

__global__ __launch_bounds__(256) void gemm_mfma1(const float* __restrict__ x,
                                                  const unsigned short* __restrict__ wt1,
                                                  uint8_t* __restrict__ t1a,
                                                  uint8_t* __restrict__ t1b) {
    const int tid = threadIdx.x;
    const int wid = tid >> 6, lane = tid & 63;
    const int l15 = lane & 15, lk = lane >> 4;
    const int n0 = blockIdx.y * 64;
    uint8_t* dst = (blockIdx.y == 0) ? t1a : t1b;

    bf16x8 bfrag[4][4];
#pragma unroll
    for (int t = 0; t < 4; ++t) {
        const unsigned short* wp = wt1 + (size_t)(n0 + t * 16 + l15) * 128 + lk * 8;
#pragma unroll
        for (int s = 0; s < 4; ++s)
            bfrag[t][s] = *reinterpret_cast<const bf16x8*>(wp + s * 32);
    }

    for (int mt = blockIdx.x * 4 + wid; mt < 3125; mt += 784) {
        const int arow = mt * 16 + l15;
        bf16x8 afrag[4];
        const float* ap = x + (size_t)arow * 128 + lk * 8;
#pragma unroll
        for (int s = 0; s < 4; ++s) {
            float4 p0 = *reinterpret_cast<const float4*>(ap + s * 32);
            float4 p1 = *reinterpret_cast<const float4*>(ap + s * 32 + 4);
            bf16x8 f;
            f[0] = (short)f2bf(p0.x); f[1] = (short)f2bf(p0.y);
            f[2] = (short)f2bf(p0.z); f[3] = (short)f2bf(p0.w);
            f[4] = (short)f2bf(p1.x); f[5] = (short)f2bf(p1.y);
            f[6] = (short)f2bf(p1.z); f[7] = (short)f2bf(p1.w);
            afrag[s] = f;
        }

        f32x4 acc[4] = {{0.f,0.f,0.f,0.f},{0.f,0.f,0.f,0.f},{0.f,0.f,0.f,0.f},{0.f,0.f,0.f,0.f}};
#pragma unroll
        for (int s = 0; s < 4; ++s)
#pragma unroll
            for (int t = 0; t < 4; ++t)
                acc[t] = __builtin_amdgcn_mfma_f32_16x16x32_bf16(afrag[s], bfrag[t][s], acc[t], 0, 0, 0);

#pragma unroll
        for (int t = 0; t < 4; ++t)
#pragma unroll
            for (int q = 0; q < 4; ++q) {
                int r = mt * 16 + lk * 4 + q;
                dst[(size_t)r * 64 + t * 16 + l15] = f2fp8(acc[t][q]);
            }
    }
}

// ---------------- gemm2: {t2a,t2b}[M,32](bf16 u16) = bf16(hpk @ W2), column-split ----------------

__global__ __launch_bounds__(256) void gemm_mfma2(const uint32_t* __restrict__ Apk,
                                                  const unsigned short* __restrict__ Wt,
                                                  unsigned short* __restrict__ t2a,
                                                  unsigned short* __restrict__ t2b) {
    const int tid = threadIdx.x;
    const int wid = tid >> 6, lane = tid & 63;
    const int l15 = lane & 15, lk = lane >> 4;

    bf16x8 bfrag[4][4];
#pragma unroll
    for (int t = 0; t < 4; ++t) {
        const unsigned short* wp = Wt + (size_t)(t * 16 + l15) * 128 + lk * 8;
#pragma unroll
        for (int s = 0; s < 4; ++s)
            bfrag[t][s] = *reinterpret_cast<const bf16x8*>(wp + s * 32);
    }

    for (int mt = blockIdx.x * 4 + wid; mt < 3125; mt += 784) {
        const int arow = mt * 16 + l15;
        bf16x8 afrag[4];
        const uint32_t* ap = Apk + (size_t)arow * 64 + lk * 4;
#pragma unroll
        for (int s = 0; s < 4; ++s)
            afrag[s] = *reinterpret_cast<const bf16x8*>(ap + s * 16);

        f32x4 acc[4] = {{0.f,0.f,0.f,0.f},{0.f,0.f,0.f,0.f},{0.f,0.f,0.f,0.f},{0.f,0.f,0.f,0.f}};
#pragma unroll
        for (int s = 0; s < 4; ++s)
#pragma unroll
            for (int t = 0; t < 4; ++t)
                acc[t] = __builtin_amdgcn_mfma_f32_16x16x32_bf16(afrag[s], bfrag[t][s], acc[t], 0, 0, 0);

#pragma unroll
        for (int t = 0; t < 4; ++t)
#pragma unroll
            for (int q = 0; q < 4; ++q) {
                int r = mt * 16 + lk * 4 + q;
                int d = t * 16 + l15;                         // 0..63
                unsigned short* dst = (d < 32) ? t2a : t2b;
                dst[(size_t)r * 32 + (d & 31)] = f2bf(acc[t][q]);
            }
    }
}

// ---------------- SPMM half-pass, fp8 operand (layer 1) ----------------
// x8h is [N][64] fp8 (3.2MB, per-XCD-L2 resident); half-wave (32 lanes) per edge,
// lane j handles dims {2j,2j+1} of this half; writes hpk words [word_off, word_off+32).

__global__ __launch_bounds__(256) void spmm_half_fp8(const int* __restrict__ counts,
                                                     const uint32_t* __restrict__ ell,
                                                     const uint8_t* __restrict__ x8h,
                                                     uint32_t* __restrict__ outp,
                                                     int word_off) {
    __shared__ float lut[256];
    {
        int b = threadIdx.x;               // block is exactly 256 threads
        uint32_t ee = (b >> 3) & 15u, mm = b & 7u;
        float f = (ee == 0) ? ldexpf((float)mm, -9) : ldexpf((float)(8 + mm), (int)ee - 10);
        lut[b] = (b & 0x80) ? -f : f;
    }
    __syncthreads();

    const int wid = threadIdx.x >> 6;
    const int lane = threadIdx.x & 63;
    const int r = blockIdx.x * 4 + wid;
    if (r >= N_NODES) return;
    const int start = r << 6;
    int cnt = counts[r]; if (cnt > ELL_CAP) cnt = ELL_CAP;
    const int end = start + cnt;
    const int j = lane & 31;
    const int half = lane >> 5;
    const uint8_t* xb = x8h + j * 2;

    float alo[4] = {0.f, 0.f, 0.f, 0.f};
    float ahi[4] = {0.f, 0.f, 0.f, 0.f};
    int e = start + half;
    for (; e + 6 < end; e += 8) {
        uint32_t c0 = ell[e], c1 = ell[e + 2], c2 = ell[e + 4], c3 = ell[e + 6];
        unsigned short u0 = *reinterpret_cast<const unsigned short*>(xb + (size_t)(c0 & 0xffffu) * 64);
        unsigned short u1 = *reinterpret_cast<const unsigned short*>(xb + (size_t)(c1 & 0xffffu) * 64);
        unsigned short u2 = *reinterpret_cast<const unsigned short*>(xb + (size_t)(c2 & 0xffffu) * 64);
        unsigned short u3 = *reinterpret_cast<const unsigned short*>(xb + (size_t)(c3 & 0xffffu) * 64);
        float v0 = __uint_as_float(c0 & 0xffff0000u), v1 = __uint_as_float(c1 & 0xffff0000u);
        float v2 = __uint_as_float(c2 & 0xffff0000u), v3 = __uint_as_float(c3 & 0xffff0000u);
        alo[0] = fmaf(v0, lut[u0 & 0xff], alo[0]); ahi[0] = fmaf(v0, lut[u0 >> 8], ahi[0]);
        alo[1] = fmaf(v1, lut[u1 & 0xff], alo[1]); ahi[1] = fmaf(v1, lut[u1 >> 8], ahi[1]);
        alo[2] = fmaf(v2, lut[u2 & 0xff], alo[2]); ahi[2] = fmaf(v2, lut[u2 >> 8], ahi[2]);
        alo[3] = fmaf(v3, lut[u3 & 0xff], alo[3]); ahi[3] = fmaf(v3, lut[u3 >> 8], ahi[3]);
    }
    for (; e < end; e += 2) {
        uint32_t c0 = ell[e];
        float v = __uint_as_float(c0 & 0xffff0000u);
        unsigned short u = *reinterpret_cast<const unsigned short*>(xb + (size_t)(c0 & 0xffffu) * 64);
        alo[0] = fmaf(v, lut[u & 0xff], alo[0]); ahi[0] = fmaf(v, lut[u >> 8], ahi[0]);
    }
    float rlo = (alo[0] + alo[1]) + (alo[2] + alo[3]);
    float rhi = (ahi[0] + ahi[1]) + (ahi[2] + ahi[3]);
    rlo += __shfl_xor(rlo, 32);
    rhi += __shfl_xor(rhi, 32);
    if (half == 0) {
        rlo = fmaxf(rlo, 0.f);    // RELU (layer 1)
        rhi = fmaxf(rhi, 0.f);
        outp[(size_t)r * 64 + word_off + j] = pack_bf16x2(rlo, rhi);
    }
}

// ---------------- SPMM half-pass, bf16 operand (layer 2) ----------------
// xph is [N][16]u32 (3.2MB, per-XCD-L2 resident); quarter-wave (16 lanes) per edge,
// lane j handles dims {2j,2j+1} of this half; writes out dims [dim_off, dim_off+32).

__global__ __launch_bounds__(256) void spmm_half_bf16(const int* __restrict__ counts,
                                                      const uint32_t* __restrict__ ell,
                                                      const uint32_t* __restrict__ xph,
                                                      float* __restrict__ out,
                                                      int dim_off) {
    const int wid = threadIdx.x >> 6;
    const int lane = threadIdx.x & 63;
    const int r = blockIdx.x * 4 + wid;
    if (r >= N_NODES) return;
    const int start = r << 6;
    int cnt = counts[r]; if (cnt > ELL_CAP) cnt = ELL_CAP;
    const int end = start + cnt;
    const int j = lane & 15;
    const int g = lane >> 4;           // 0..3 edge groups
    const uint32_t* xb = xph + j;

    float alo[4] = {0.f, 0.f, 0.f, 0.f};
    float ahi[4] = {0.f, 0.f, 0.f, 0.f};
    int e = start + g;
    for (; e + 12 < end; e += 16) {
        uint32_t c0 = ell[e], c1 = ell[e + 4], c2 = ell[e + 8], c3 = ell[e + 12];
        uint32_t u0 = xb[(size_t)(c0 & 0xffffu) * 16];
        uint32_t u1 = xb[(size_t)(c1 & 0xffffu) * 16];
        uint32_t u2 = xb[(size_t)(c2 & 0xffffu) * 16];
        uint32_t u3 = xb[(size_t)(c3 & 0xffffu) * 16];
        float v0 = __uint_as_float(c0 & 0xffff0000u), v1 = __uint_as_float(c1 & 0xffff0000u);
        float v2 = __uint_as_float(c2 & 0xffff0000u), v3 = __uint_as_float(c3 & 0xffff0000u);
        alo[0] = fmaf(v0, __uint_as_float(u0 << 16), alo[0]);
        ahi[0] = fmaf(v0, __uint_as_float(u0 & 0xffff0000u), ahi[0]);
        alo[1] = fmaf(v1, __uint_as_float(u1 << 16), alo[1]);
        ahi[1] = fmaf(v1, __uint_as_float(u1 & 0xffff0000u), ahi[1]);
        alo[2] = fmaf(v2, __uint_as_float(u2 << 16), alo[2]);
        ahi[2] = fmaf(v2, __uint_as_float(u2 & 0xffff0000u), ahi[2]);
        alo[3] = fmaf(v3, __uint_as_float(u3 << 16), alo[3]);
        ahi[3] = fmaf(v3, __uint_as_float(u3 & 0xffff0000u), ahi[3]);
    }
    for (; e < end; e += 4) {
        uint32_t c0 = ell[e];
        float v = __uint_as_float(c0 & 0xffff0000u);
        uint32_t u = xb[(size_t)(c0 & 0xffffu) * 16];
        alo[0] = fmaf(v, __uint_as_float(u << 16), alo[0]);
        ahi[0] = fmaf(v, __uint_as_float(u & 0xffff0000u), ahi[0]);
    }
    float alo_s = (alo[0] + alo[1]) + (alo[2] + alo[3]);
    float ahi_s = (ahi[0] + ahi[1]) + (ahi[2] + ahi[3]);
    alo_s += __shfl_xor(alo_s, 16);
    ahi_s += __shfl_xor(ahi_s, 16);
    alo_s += __shfl_xor(alo_s, 32);
    ahi_s += __shfl_xor(ahi_s, 32);
    if (lane < 16) {
        float2 res = {alo_s, ahi_s};
        *reinterpret_cast<float2*>(out + (size_t)r * 64 + dim_off + j * 2) = res;
    }
}

// ---------------- launch (8 dispatches) ----------------

extern "C" void kernel_launch(void* const* d_in, const int* in_sizes, int n_in,
                              void* d_out, int out_size, void* d_ws, size_t ws_size,
                              hipStream_t stream) {
    const float* x    = (const float*)d_in[0];
    const int*   row  = (const int*)  d_in[1];
    const int*   col  = (const int*)  d_in[2];
    const float* vals = (const float*)d_in[3];
    const float* W1   = (const float*)d_in[4];
    const float* W2   = (const float*)d_in[5];
    float* out = (float*)d_out;

    // workspace layout (256B-aligned chunks)
    char* ws = (char*)d_ws;
    auto align = [](size_t v) { return (v + 255) & ~(size_t)255; };
    int*      counts  = (int*)ws;              ws += align(sizeof(int) * N_NODES);
    uint32_t* epk     = (uint32_t*)ws;         ws += align(sizeof(uint32_t) * N_EDGES);
    uint32_t* ell     = (uint32_t*)ws;         ws += align(sizeof(uint32_t) * N_NODES * ELL_CAP);
    uint8_t*  t1a     = (uint8_t*)ws;          ws += align(sizeof(uint8_t) * N_NODES * 64);
    uint8_t*  t1b     = (uint8_t*)ws;          ws += align(sizeof(uint8_t) * N_NODES * 64);
    uint32_t* hpk     = (uint32_t*)ws;         ws += align(sizeof(uint32_t) * N_NODES * 64);
    unsigned short* t2a = (unsigned short*)ws; ws += align(sizeof(short) * N_NODES * 32);
    unsigned short* t2b = (unsigned short*)ws; ws += align(sizeof(short) * N_NODES * 32);
    unsigned short* wt1 = (unsigned short*)ws; ws += align(sizeof(short) * 128 * 128);
    unsigned short* wt2 = (unsigned short*)ws; ws += align(sizeof(short) * 64 * 128);

    // ---- init: zero counts, convert weights, pre-pack (col,val) ----
    init_all<<<INIT_BLOCKS, 256, 0, stream>>>(counts, W1, W2, wt1, wt2, col, vals, epk);

    // ---- ELL scatter ----
    scatter_ell<<<SCAT_BLOCKS, 256, 0, stream>>>(row, epk, counts, ell);

    // ---- layer 1: {t1a,t1b} = fp8(x @ W1); h = bf16(relu(A @ t1)) in two L2-fit passes ----
    gemm_mfma1<<<dim3(196, 2), 256, 0, stream>>>(x, wt1, t1a, t1b);
    spmm_half_fp8<<<(N_NODES + 3) / 4, 256, 0, stream>>>(counts, ell, t1a, hpk, 0);
    spmm_half_fp8<<<(N_NODES + 3) / 4, 256, 0, stream>>>(counts, ell, t1b, hpk, 32);

    // ---- layer 2: {t2a,t2b} = bf16(h @ W2); out = A @ t2 in two L2-fit passes ----
    gemm_mfma2<<<196, 256, 0, stream>>>(hpk, wt2, t2a, t2b);
    spmm_half_bf16<<<(N_NODES + 3) / 4, 256, 0, stream>>>(counts, ell, (const uint32_t*)t2a, out, 0);
    spmm_half_bf16<<<(N_NODES + 3) / 4, 256, 0, stream>>>(counts, ell, (const uint32_t*)t2b, out, 32);
}

// Round 22
// 126.538 us; speedup vs baseline: 1.2709x; 1.2709x over previous
//
#include <hip/hip_runtime.h>
#include <stdint.h>

#define N_NODES 50000
#define N_EDGES 800000
#define IN_DIM 128
#define HID_DIM 128
#define OUT_DIM 64

#define ELL_CAP 64                            // slots/row; Poisson(16) max deg ~38
#define XCD_GROUPS 8
#define ROWS_PER_XCD (N_NODES / XCD_GROUPS)   // 6250 exactly
#define SCAT_BLOCKS_PER_XCD 256
#define SCAT_BLOCKS (SCAT_BLOCKS_PER_XCD * XCD_GROUPS)   // 2048

#define INIT_BLOCKS 3300                      // 3300*256 = 844800 >= N_EDGES

typedef short bf16x8 __attribute__((ext_vector_type(8)));
typedef float f32x4  __attribute__((ext_vector_type(4)));

__device__ __forceinline__ uint32_t pack_bf16x2(float a, float b) {
    uint32_t ba = __float_as_uint(a), bb = __float_as_uint(b);
    ba = (ba + 0x7fffu + ((ba >> 16) & 1u)) >> 16;           // RNE low half
    bb = (bb + 0x7fffu + ((bb >> 16) & 1u)) & 0xffff0000u;   // RNE high half
    return ba | bb;
}

__device__ __forceinline__ unsigned short f2bf(float f) {
    uint32_t u = __float_as_uint(f);
    return (unsigned short)((u + 0x7fffu + ((u >> 16) & 1u)) >> 16);
}

// f32 -> fp8 e4m3fn, RNE, subnormals flushed, clamp at 448 (t1 ~ N(0,1): safe)
__device__ __forceinline__ uint8_t f2fp8(float f) {
    uint32_t u = __float_as_uint(f);
    uint32_t s = (u >> 24) & 0x80u;
    uint32_t au = u & 0x7fffffffu;
    uint32_t r = au + 0x7FFFFu + ((au >> 20) & 1u);   // RNE at dropped-20-bits boundary
    int e = (int)((r >> 23) & 0xffu) - 120;           // e_f32 - 127 + 7
    uint32_t m = (r >> 20) & 7u;
    uint32_t out;
    if (e <= 0) out = 0u;                             // flush tiny
    else if (e >= 16) out = 0x7Eu;                    // clamp to 448
    else out = ((uint32_t)e << 3) | m;
    return (uint8_t)(s | out);
}

// packed edge: high 16 bits = bf16(val), low 16 bits = col (col < 65536)
__device__ __forceinline__ uint32_t pack_edge(int col, float v) {
    uint32_t fb = __float_as_uint(v);
    fb = (fb + 0x7fffu + ((fb >> 16) & 1u)) & 0xffff0000u;
    return fb | (uint32_t)col;
}

// ---------------- fused init: zero counts + convert weights + pre-pack (col,val) ----------------

__global__ __launch_bounds__(256) void init_all(int* __restrict__ counts,
                                                const float* __restrict__ W1,
                                                const float* __restrict__ W2,
                                                unsigned short* __restrict__ wt1,
                                                unsigned short* __restrict__ wt2,
                                                const int* __restrict__ col,
                                                const float* __restrict__ vals,
                                                uint32_t* __restrict__ epk) {
    int i = blockIdx.x * 256 + threadIdx.x;
    if (i < N_NODES) counts[i] = 0;
    int j = i - N_NODES;
    if (j >= 0 && j < 128 * 128) {
        int n = j >> 7, k = j & 127;
        wt1[j] = f2bf(W1[k * 128 + n]);
    }
    int l = j - 128 * 128;
    if (l >= 0 && l < 64 * 128) {
        int n = l >> 7, k = l & 127;
        wt2[l] = f2bf(W2[k * 64 + n]);
    }
    if (i < N_EDGES) epk[i] = pack_edge(col[i], vals[i]);   // INIT_BLOCKS*256 >= N_EDGES
}

// ---------------- ELL build: single scatter pass, XCD-partitioned dest (structural floor ~40us) ----------------

__global__ __launch_bounds__(256) void scatter_ell(const int* __restrict__ row,
                                                   const uint32_t* __restrict__ epk,
                                                   int* __restrict__ counts,
                                                   uint32_t* __restrict__ ell) {
    const int xcd = blockIdx.x & (XCD_GROUPS - 1);
    const int blk = blockIdx.x >> 3;
    const int rlo = xcd * ROWS_PER_XCD;
    int e = blk * 256 + threadIdx.x;
    const int stride = SCAT_BLOCKS_PER_XCD * 256;
    for (; e < N_EDGES; e += stride) {
        int r = row[e];
        if ((unsigned)(r - rlo) < (unsigned)ROWS_PER_XCD) {
            int p = atomicAdd(&counts[r], 1);
            if (p < ELL_CAP)   // unreachable for Poisson(16); memory-safety guard
                ell[((size_t)r << 6) + p] = epk[e];
        }
    }
}

// ---------------- gemm1: t1f8[M,128](fp8 e4m3) = fp8(x @ W1) ----------------
// MFMA 16x16x32 bf16, HW-verified layouts:
//   A: row=lane&15, k=(lane>>4)*8+j ; B from Wt[n][k]: col=lane&15, same k
//   D: col=lane&15, row=(lane>>4)*4+reg.  50000 rows = 3125 m-tiles exactly.

__global__ __launch_bounds__(256) void gemm_mfma1(const float* __restrict__ x,
                                                  const unsigned short* __restrict__ wt1,
                                                  uint8_t* __restrict__ t1f8) {
    const int tid = threadIdx.x;
    const int wid = tid >> 6, lane = tid & 63;
    const int l15 = lane & 15, lk = lane >> 4;
    const int n0 = blockIdx.y * 64;

    bf16x8 bfrag[4][4];
#pragma unroll
    for (int t = 0; t < 4; ++t) {
        const unsigned short* wp = wt1 + (size_t)(n0 + t * 16 + l15) * 128 + lk * 8;
#pragma unroll
        for (int s = 0; s < 4; ++s)
            bfrag[t][s] = *reinterpret_cast<const bf16x8*>(wp + s * 32);
    }

    for (int mt = blockIdx.x * 4 + wid; mt < 3125; mt += 784) {
        const int arow = mt * 16 + l15;
        bf16x8 afrag[4];
        const float* ap = x + (size_t)arow * 128 + lk * 8;
#pragma unroll
        for (int s = 0; s < 4; ++s) {
            float4 p0 = *reinterpret_cast<const float4*>(ap + s * 32);
            float4 p1 = *reinterpret_cast<const float4*>(ap + s * 32 + 4);
            bf16x8 f;
            f[0] = (short)f2bf(p0.x); f[1] = (short)f2bf(p0.y);
            f[2] = (short)f2bf(p0.z); f[3] = (short)f2bf(p0.w);
            f[4] = (short)f2bf(p1.x); f[5] = (short)f2bf(p1.y);
            f[6] = (short)f2bf(p1.z); f[7] = (short)f2bf(p1.w);
            afrag[s] = f;
        }

        f32x4 acc[4] = {{0.f,0.f,0.f,0.f},{0.f,0.f,0.f,0.f},{0.f,0.f,0.f,0.f},{0.f,0.f,0.f,0.f}};
#pragma unroll
        for (int s = 0; s < 4; ++s)
#pragma unroll
            for (int t = 0; t < 4; ++t)
                acc[t] = __builtin_amdgcn_mfma_f32_16x16x32_bf16(afrag[s], bfrag[t][s], acc[t], 0, 0, 0);

#pragma unroll
        for (int t = 0; t < 4; ++t)
#pragma unroll
            for (int q = 0; q < 4; ++q) {
                int r = mt * 16 + lk * 4 + q;
                t1f8[(size_t)r * 128 + n0 + t * 16 + l15] = f2fp8(acc[t][q]);
            }
    }
}

// ---------------- gemm2 (bf16-packed A): outb[M,64](bf16) = hpk @ W2 ----------------

__global__ __launch_bounds__(256) void gemm_mfma2(const uint32_t* __restrict__ Apk,
                                                  const unsigned short* __restrict__ Wt,
                                                  unsigned short* __restrict__ outb) {
    const int tid = threadIdx.x;
    const int wid = tid >> 6, lane = tid & 63;
    const int l15 = lane & 15, lk = lane >> 4;

    bf16x8 bfrag[4][4];
#pragma unroll
    for (int t = 0; t < 4; ++t) {
        const unsigned short* wp = Wt + (size_t)(t * 16 + l15) * 128 + lk * 8;
#pragma unroll
        for (int s = 0; s < 4; ++s)
            bfrag[t][s] = *reinterpret_cast<const bf16x8*>(wp + s * 32);
    }

    for (int mt = blockIdx.x * 4 + wid; mt < 3125; mt += 784) {
        const int arow = mt * 16 + l15;
        bf16x8 afrag[4];
        const uint32_t* ap = Apk + (size_t)arow * 64 + lk * 4;
#pragma unroll
        for (int s = 0; s < 4; ++s)
            afrag[s] = *reinterpret_cast<const bf16x8*>(ap + s * 16);

        f32x4 acc[4] = {{0.f,0.f,0.f,0.f},{0.f,0.f,0.f,0.f},{0.f,0.f,0.f,0.f},{0.f,0.f,0.f,0.f}};
#pragma unroll
        for (int s = 0; s < 4; ++s)
#pragma unroll
            for (int t = 0; t < 4; ++t)
                acc[t] = __builtin_amdgcn_mfma_f32_16x16x32_bf16(afrag[s], bfrag[t][s], acc[t], 0, 0, 0);

#pragma unroll
        for (int t = 0; t < 4; ++t)
#pragma unroll
            for (int q = 0; q < 4; ++q) {
                int r = mt * 16 + lk * 4 + q;
                outb[(size_t)r * 64 + t * 16 + l15] = f2bf(acc[t][q]);
            }
    }
}

// ---------------- ELL SPMM, fp8 operand (layer 1), f32 accumulate, bf16-packed out ----------------
// x8 is [N][128] fp8 e4m3; lane handles dims {2l,2l+1} via 2B load + LDS LUT decode.

template<bool RELU>
__global__ __launch_bounds__(256) void spmm_fp8_128(const int* __restrict__ counts,
                                                    const uint32_t* __restrict__ ell,
                                                    const uint8_t* __restrict__ x8,
                                                    uint32_t* __restrict__ outp) {
    __shared__ float lut[256];
    {
        int b = threadIdx.x;               // block is exactly 256 threads
        uint32_t ee = (b >> 3) & 15u, mm = b & 7u;
        float f = (ee == 0) ? ldexpf((float)mm, -9) : ldexpf((float)(8 + mm), (int)ee - 10);
        lut[b] = (b & 0x80) ? -f : f;
    }
    __syncthreads();

    const int wid = threadIdx.x >> 6;
    const int lane = threadIdx.x & 63;
    const int r = blockIdx.x * 4 + wid;
    if (r >= N_NODES) return;
    const int start = r << 6;
    int cnt = counts[r]; if (cnt > ELL_CAP) cnt = ELL_CAP;
    const int end = start + cnt;
    const uint8_t* xb = x8 + lane * 2;

    float alo[4] = {0.f, 0.f, 0.f, 0.f};
    float ahi[4] = {0.f, 0.f, 0.f, 0.f};
    int e = start;
    for (; e + 7 < end; e += 8) {
        uint32_t c0 = ell[e],     c1 = ell[e + 1], c2 = ell[e + 2], c3 = ell[e + 3];
        uint32_t c4 = ell[e + 4], c5 = ell[e + 5], c6 = ell[e + 6], c7 = ell[e + 7];
        unsigned short u0 = *reinterpret_cast<const unsigned short*>(xb + (size_t)(c0 & 0xffffu) * 128);
        unsigned short u1 = *reinterpret_cast<const unsigned short*>(xb + (size_t)(c1 & 0xffffu) * 128);
        unsigned short u2 = *reinterpret_cast<const unsigned short*>(xb + (size_t)(c2 & 0xffffu) * 128);
        unsigned short u3 = *reinterpret_cast<const unsigned short*>(xb + (size_t)(c3 & 0xffffu) * 128);
        unsigned short u4 = *reinterpret_cast<const unsigned short*>(xb + (size_t)(c4 & 0xffffu) * 128);
        unsigned short u5 = *reinterpret_cast<const unsigned short*>(xb + (size_t)(c5 & 0xffffu) * 128);
        unsigned short u6 = *reinterpret_cast<const unsigned short*>(xb + (size_t)(c6 & 0xffffu) * 128);
        unsigned short u7 = *reinterpret_cast<const unsigned short*>(xb + (size_t)(c7 & 0xffffu) * 128);
        float v0 = __uint_as_float(c0 & 0xffff0000u), v1 = __uint_as_float(c1 & 0xffff0000u);
        float v2 = __uint_as_float(c2 & 0xffff0000u), v3 = __uint_as_float(c3 & 0xffff0000u);
        float v4 = __uint_as_float(c4 & 0xffff0000u), v5 = __uint_as_float(c5 & 0xffff0000u);
        float v6 = __uint_as_float(c6 & 0xffff0000u), v7 = __uint_as_float(c7 & 0xffff0000u);
        alo[0] = fmaf(v0, lut[u0 & 0xff], alo[0]); ahi[0] = fmaf(v0, lut[u0 >> 8], ahi[0]);
        alo[1] = fmaf(v1, lut[u1 & 0xff], alo[1]); ahi[1] = fmaf(v1, lut[u1 >> 8], ahi[1]);
        alo[2] = fmaf(v2, lut[u2 & 0xff], alo[2]); ahi[2] = fmaf(v2, lut[u2 >> 8], ahi[2]);
        alo[3] = fmaf(v3, lut[u3 & 0xff], alo[3]); ahi[3] = fmaf(v3, lut[u3 >> 8], ahi[3]);
        alo[0] = fmaf(v4, lut[u4 & 0xff], alo[0]); ahi[0] = fmaf(v4, lut[u4 >> 8], ahi[0]);
        alo[1] = fmaf(v5, lut[u5 & 0xff], alo[1]); ahi[1] = fmaf(v5, lut[u5 >> 8], ahi[1]);
        alo[2] = fmaf(v6, lut[u6 & 0xff], alo[2]); ahi[2] = fmaf(v6, lut[u6 >> 8], ahi[2]);
        alo[3] = fmaf(v7, lut[u7 & 0xff], alo[3]); ahi[3] = fmaf(v7, lut[u7 >> 8], ahi[3]);
    }
    if (e + 3 < end) {
        uint32_t c0 = ell[e], c1 = ell[e + 1], c2 = ell[e + 2], c3 = ell[e + 3];
        unsigned short u0 = *reinterpret_cast<const unsigned short*>(xb + (size_t)(c0 & 0xffffu) * 128);
        unsigned short u1 = *reinterpret_cast<const unsigned short*>(xb + (size_t)(c1 & 0xffffu) * 128);
        unsigned short u2 = *reinterpret_cast<const unsigned short*>(xb + (size_t)(c2 & 0xffffu) * 128);
        unsigned short u3 = *reinterpret_cast<const unsigned short*>(xb + (size_t)(c3 & 0xffffu) * 128);
        float v0 = __uint_as_float(c0 & 0xffff0000u), v1 = __uint_as_float(c1 & 0xffff0000u);
        float v2 = __uint_as_float(c2 & 0xffff0000u), v3 = __uint_as_float(c3 & 0xffff0000u);
        alo[0] = fmaf(v0, lut[u0 & 0xff], alo[0]); ahi[0] = fmaf(v0, lut[u0 >> 8], ahi[0]);
        alo[1] = fmaf(v1, lut[u1 & 0xff], alo[1]); ahi[1] = fmaf(v1, lut[u1 >> 8], ahi[1]);
        alo[2] = fmaf(v2, lut[u2 & 0xff], alo[2]); ahi[2] = fmaf(v2, lut[u2 >> 8], ahi[2]);
        alo[3] = fmaf(v3, lut[u3 & 0xff], alo[3]); ahi[3] = fmaf(v3, lut[u3 >> 8], ahi[3]);
        e += 4;
    }
    for (; e < end; ++e) {
        uint32_t c0 = ell[e];
        float v0 = __uint_as_float(c0 & 0xffff0000u);
        unsigned short u0 = *reinterpret_cast<const unsigned short*>(xb + (size_t)(c0 & 0xffffu) * 128);
        alo[0] = fmaf(v0, lut[u0 & 0xff], alo[0]); ahi[0] = fmaf(v0, lut[u0 >> 8], ahi[0]);
    }
    float rlo = (alo[0] + alo[1]) + (alo[2] + alo[3]);
    float rhi = (ahi[0] + ahi[1]) + (ahi[2] + ahi[3]);
    if (RELU) { rlo = fmaxf(rlo, 0.f); rhi = fmaxf(rhi, 0.f); }
    outp[(size_t)r * 64 + lane] = pack_bf16x2(rlo, rhi);
}

// ---------------- ELL SPMM D=64, bf16 operand ----------------

__global__ __launch_bounds__(256) void spmm_bf16_64(const int* __restrict__ counts,
                                                    const uint32_t* __restrict__ ell,
                                                    const uint32_t* __restrict__ xp,
                                                    float* __restrict__ out) {
    const int wid = threadIdx.x >> 6;
    const int lane = threadIdx.x & 63;
    const int r = blockIdx.x * 4 + wid;
    if (r >= N_NODES) return;
    const int start = r << 6;
    int cnt = counts[r]; if (cnt > ELL_CAP) cnt = ELL_CAP;
    const int end = start + cnt;
    const int j = lane & 31;
    const int half = lane >> 5;
    const uint32_t* xb = xp + j;

    float alo[4] = {0.f, 0.f, 0.f, 0.f};
    float ahi[4] = {0.f, 0.f, 0.f, 0.f};
    int e = start + half;
    for (; e + 6 < end; e += 8) {
        uint32_t c0 = ell[e], c1 = ell[e + 2], c2 = ell[e + 4], c3 = ell[e + 6];
        uint32_t u0 = xb[(size_t)(c0 & 0xffffu) * 32];
        uint32_t u1 = xb[(size_t)(c1 & 0xffffu) * 32];
        uint32_t u2 = xb[(size_t)(c2 & 0xffffu) * 32];
        uint32_t u3 = xb[(size_t)(c3 & 0xffffu) * 32];
        float v0 = __uint_as_float(c0 & 0xffff0000u), v1 = __uint_as_float(c1 & 0xffff0000u);
        float v2 = __uint_as_float(c2 & 0xffff0000u), v3 = __uint_as_float(c3 & 0xffff0000u);
        alo[0] = fmaf(v0, __uint_as_float(u0 << 16), alo[0]);
        ahi[0] = fmaf(v0, __uint_as_float(u0 & 0xffff0000u), ahi[0]);
        alo[1] = fmaf(v1, __uint_as_float(u1 << 16), alo[1]);
        ahi[1] = fmaf(v1, __uint_as_float(u1 & 0xffff0000u), ahi[1]);
        alo[2] = fmaf(v2, __uint_as_float(u2 << 16), alo[2]);
        ahi[2] = fmaf(v2, __uint_as_float(u2 & 0xffff0000u), ahi[2]);
        alo[3] = fmaf(v3, __uint_as_float(u3 << 16), alo[3]);
        ahi[3] = fmaf(v3, __uint_as_float(u3 & 0xffff0000u), ahi[3]);
    }
    for (; e < end; e += 2) {
        uint32_t c0 = ell[e];
        float v = __uint_as_float(c0 & 0xffff0000u);
        uint32_t u = xb[(size_t)(c0 & 0xffffu) * 32];
        alo[0] = fmaf(v, __uint_as_float(u << 16), alo[0]);
        ahi[0] = fmaf(v, __uint_as_float(u & 0xffff0000u), ahi[0]);
    }
    float alo_s = (alo[0] + alo[1]) + (alo[2] + alo[3]);
    float ahi_s = (ahi[0] + ahi[1]) + (ahi[2] + ahi[3]);
    alo_s += __shfl_xor(alo_s, 32);
    ahi_s += __shfl_xor(ahi_s, 32);
    if (half == 0) {
        float2 res = {alo_s, ahi_s};
        *reinterpret_cast<float2*>(out + (size_t)r * 64 + j * 2) = res;
    }
}

// ---------------- launch (6 dispatches) ----------------

extern "C" void kernel_launch(void* const* d_in, const int* in_sizes, int n_in,
                              void* d_out, int out_size, void* d_ws, size_t ws_size,
                              hipStream_t stream) {
    const float* x    = (const float*)d_in[0];
    const int*   row  = (const int*)  d_in[1];
    const int*   col  = (const int*)  d_in[2];
    const float* vals = (const float*)d_in[3];
    const float* W1   = (const float*)d_in[4];
    const float* W2   = (const float*)d_in[5];
    float* out = (float*)d_out;

    // workspace layout (256B-aligned chunks)
    char* ws = (char*)d_ws;
    auto align = [](size_t v) { return (v + 255) & ~(size_t)255; };
    int*      counts  = (int*)ws;              ws += align(sizeof(int) * N_NODES);
    uint32_t* epk     = (uint32_t*)ws;         ws += align(sizeof(uint32_t) * N_EDGES);
    uint32_t* ell     = (uint32_t*)ws;         ws += align(sizeof(uint32_t) * N_NODES * ELL_CAP);
    uint8_t*  t1f8    = (uint8_t*)ws;          ws += align(sizeof(uint8_t) * N_NODES * 128);
    uint32_t* hpk     = (uint32_t*)ws;         ws += align(sizeof(uint32_t) * N_NODES * 64);
    uint32_t* tpk     = (uint32_t*)ws;         ws += align(sizeof(uint32_t) * N_NODES * 32);
    unsigned short* wt1 = (unsigned short*)ws; ws += align(sizeof(short) * 128 * 128);
    unsigned short* wt2 = (unsigned short*)ws; ws += align(sizeof(short) * 64 * 128);

    // ---- init: zero counts, convert weights, pre-pack (col,val) ----
    init_all<<<INIT_BLOCKS, 256, 0, stream>>>(counts, W1, W2, wt1, wt2, col, vals, epk);

    // ---- ELL scatter ----
    scatter_ell<<<SCAT_BLOCKS, 256, 0, stream>>>(row, epk, counts, ell);

    // ---- layer 1: t1 = fp8(x @ W1); h = bf16(relu(A @ t1)) ----
    gemm_mfma1<<<dim3(196, 2), 256, 0, stream>>>(x, wt1, t1f8);
    spmm_fp8_128<true><<<(N_NODES + 3) / 4, 256, 0, stream>>>(counts, ell, t1f8, hpk);

    // ---- layer 2: t2 = bf16(h @ W2); out = A @ t2 ----
    gemm_mfma2<<<196, 256, 0, stream>>>(hpk, wt2, (unsigned short*)tpk);
    spmm_bf16_64<<<(N_NODES + 3) / 4, 256, 0, stream>>>(counts, ell, tpk, out);
}